// Round 6
// baseline (81.115 us; speedup 1.0000x reference)
//
#include <hip/hip_runtime.h>

#define NUM_CLASSES 6
#define NUM_SUBJECTS 16
#define NUM_PAIRS (NUM_CLASSES * NUM_SUBJECTS)   // 96
#define MARGIN 1.0f
#define EPS 1e-6f
#define INF_I 0x7fffffff

typedef _Float16 h2_t __attribute__((ext_vector_type(2)));

// ---------------- ws layout (bytes) ----------------
// [0)      int   min1[96]
// [384)    int   min2[96]
// [768)    int   cntPos[96]
// [1152)   int   cntSbj[16]
// [1216)   u64   best[96]        packed (sortable_f32(d2)<<32)|idx
// [1984)   float a2[96]
// [2432)   f32   anchors[96*256] (float4-aligned)

__device__ __forceinline__ float wredsum(float v) {
#pragma unroll
    for (int m = 32; m >= 1; m >>= 1) v += __shfl_xor(v, m, 64);
    return v;
}

__device__ __forceinline__ unsigned int fkey(float f) {
    unsigned int b = __float_as_uint(f);
    return (b & 0x80000000u) ? ~b : (b | 0x80000000u);
}

// f32 pair -> packed f16x2 (RTZ pack instr), as _Float16 vector via bit_cast
__device__ __forceinline__ h2_t pk16(float x, float y) {
    return __builtin_bit_cast(h2_t, __builtin_amdgcn_cvt_pkrtz(x, y));
}

__global__ void k_init(int* min1, int* min2, int* cntPos, int* cntSbj,
                       unsigned long long* best, float* a2) {
    int t = threadIdx.x;
    if (t < NUM_PAIRS) {
        min1[t] = INF_I;
        min2[t] = INF_I;
        cntPos[t] = 0;
        best[t] = ~0ull;
        a2[t] = 0.f;
    }
    if (t < NUM_SUBJECTS) cntSbj[t] = 0;
}

// Fused: first-two-positive mining + counts, single pass.
__global__ void k_stats(const int* __restrict__ labels, const int* __restrict__ sbj,
                        int* min1, int* min2, int* cntPos, int* cntSbj, int B) {
    __shared__ int l1[NUM_PAIRS], l2[NUM_PAIRS], lcp[NUM_PAIRS], lcs[NUM_SUBJECTS];
    for (int t = threadIdx.x; t < NUM_PAIRS; t += blockDim.x) { l1[t] = INF_I; l2[t] = INF_I; lcp[t] = 0; }
    if (threadIdx.x < NUM_SUBJECTS) lcs[threadIdx.x] = 0;
    __syncthreads();
    int i = blockIdx.x * blockDim.x + threadIdx.x;
    if (i < B) {
        int s = sbj[i], c = labels[i];
        int p = s * NUM_CLASSES + c;
        int o = atomicMin(&l1[p], i);
        atomicMin(&l2[p], max(o, i));
        atomicAdd(&lcp[p], 1);
        atomicAdd(&lcs[s], 1);
    }
    __syncthreads();
    for (int t = threadIdx.x; t < NUM_PAIRS; t += blockDim.x) {
        int m1 = l1[t];
        if (m1 != INF_I) {
            int o = atomicMin(&min1[t], m1);
            atomicMin(&min2[t], max(o, m1));
            if (l2[t] != INF_I) atomicMin(&min2[t], l2[t]);
            atomicAdd(&cntPos[t], lcp[t]);
        }
    }
    if (threadIdx.x < NUM_SUBJECTS && lcs[threadIdx.x]) atomicAdd(&cntSbj[threadIdx.x], lcs[threadIdx.x]);
}

__global__ void k_gather(const float4* __restrict__ emb4, const int* __restrict__ min1,
                         float4* anchors4, float* a2, int B) {
    int p = blockIdx.x;          // 96 blocks
    int lane = threadIdx.x;      // 64 threads
    int idx = min1[p];
    if (idx < 0 || idx >= B) idx = 0;
    float4 v = emb4[(size_t)idx * 64 + lane];
    anchors4[(size_t)p * 64 + lane] = v;
    float t = v.x * v.x + v.y * v.y + v.z * v.z + v.w * v.w;
    t = wredsum(t);
    if (lane == 0) a2[p] = t;
}

// Natural-order streaming mine: 2 lanes per sample (each lane owns a
// contiguous 512 B half-row), 32 samples/wave, 8 waves/block, 2 blocks/CU
// -> 16 waves/CU. Anchors f16 in LDS, u64[s*385 + c*64 + e]: subject
// stride 3080 B == 8 (mod 128) -> 16 subjects on 16 distinct bank-pairs;
// halves differ by 256 B == 0 (mod 128) -> 2-way broadcast (free).
__global__ __launch_bounds__(512, 4) void k_mine(const float4* __restrict__ emb4,
                                                 const int* __restrict__ labels,
                                                 const int* __restrict__ sbj,
                                                 const float4* __restrict__ anchors4,
                                                 const float* __restrict__ a2,
                                                 unsigned long long* gbest, int B) {
    __shared__ unsigned long long ancB[NUM_SUBJECTS * 385];   // 49280 B
    __shared__ float a2l[NUM_PAIRS];
    __shared__ unsigned long long lbest[NUM_PAIRS];

    // stage anchors f32 -> f16x4 (pkrtz) packed u64
    for (int u = threadIdx.x; u < NUM_PAIRS * 64; u += blockDim.x) {
        int row = u >> 6;            // s*6+c
        int e = u & 63;              // u64 index within row (4 dims)
        float4 v = anchors4[u];
        unsigned int lou = __builtin_bit_cast(unsigned int, pk16(v.x, v.y));
        unsigned int hiu = __builtin_bit_cast(unsigned int, pk16(v.z, v.w));
        int s = row / NUM_CLASSES, c = row - s * NUM_CLASSES;
        ancB[s * 385 + c * 64 + e] = (unsigned long long)lou | ((unsigned long long)hiu << 32);
    }
    for (int t = threadIdx.x; t < NUM_PAIRS; t += blockDim.x) {
        a2l[t] = a2[t];
        lbest[t] = ~0ull;
    }
    __syncthreads();

    const int lane = threadIdx.x & 63;
    const int h = lane & 1;                         // half-row
    const int wv = (int)(threadIdx.x >> 6);         // 0..7
    const int sample = (int)blockIdx.x * 256 + wv * 32 + (lane >> 1);
    const bool valid = sample < B;
    const int ic = valid ? sample : (B - 1);
    const int s = sbj[ic];
    const int lbl = labels[ic];
    const float4* row = emb4 + (size_t)ic * 64 + h * 32;     // 32 float4 = half row
    const unsigned long long* anc = ancB + s * 385 + h * 32;

    float e2 = 0.f, d0 = 0.f, d1 = 0.f, d2v = 0.f, d3 = 0.f, d4 = 0.f, d5 = 0.f;
#pragma unroll 4
    for (int k = 0; k < 32; ++k) {
        float4 v = row[k];
        e2 = fmaf(v.x, v.x, fmaf(v.y, v.y, fmaf(v.z, v.z, fmaf(v.w, v.w, e2))));
        h2_t vlo = pk16(v.x, v.y);
        h2_t vhi = pk16(v.z, v.w);
        unsigned long long A;
        h2_t alo, ahi;
#if __has_builtin(__builtin_amdgcn_fdot2)
#define DOT(C, ACC)                                                              \
        A = anc[(C) * 64 + k];                                                   \
        alo = __builtin_bit_cast(h2_t, (unsigned int)A);                         \
        ahi = __builtin_bit_cast(h2_t, (unsigned int)(A >> 32));                 \
        ACC = __builtin_amdgcn_fdot2(alo, vlo,                                   \
              __builtin_amdgcn_fdot2(ahi, vhi, ACC, false), false);
#else
#define DOT(C, ACC)                                                              \
        A = anc[(C) * 64 + k];                                                   \
        alo = __builtin_bit_cast(h2_t, (unsigned int)A);                         \
        ahi = __builtin_bit_cast(h2_t, (unsigned int)(A >> 32));                 \
        ACC = fmaf((float)alo.x, v.x, fmaf((float)alo.y, v.y,                    \
              fmaf((float)ahi.x, v.z, fmaf((float)ahi.y, v.w, ACC))));
#endif
        DOT(0, d0) DOT(1, d1) DOT(2, d2v) DOT(3, d3) DOT(4, d4) DOT(5, d5)
#undef DOT
    }
    // combine the two half-rows (partner lane^1)
    e2  += __shfl_xor(e2, 1, 64);
    d0  += __shfl_xor(d0, 1, 64);
    d1  += __shfl_xor(d1, 1, 64);
    d2v += __shfl_xor(d2v, 1, 64);
    d3  += __shfl_xor(d3, 1, 64);
    d4  += __shfl_xor(d4, 1, 64);
    d5  += __shfl_xor(d5, 1, 64);

    if (valid && h == 0) {
        int pb = s * NUM_CLASSES;
        float dc[NUM_CLASSES] = {d0, d1, d2v, d3, d4, d5};
#pragma unroll
        for (int c = 0; c < NUM_CLASSES; ++c) {
            if (c != lbl) {
                float dd = a2l[pb + c] + e2 - 2.f * dc[c];
                unsigned long long pk =
                    ((unsigned long long)fkey(dd) << 32) | (unsigned int)sample;
                atomicMin(&lbest[pb + c], pk);
            }
        }
    }
    __syncthreads();
    for (int t = threadIdx.x; t < NUM_PAIRS; t += blockDim.x) {
        unsigned long long v = lbest[t];
        if (v != ~0ull) {
            unsigned long long cur = gbest[t];   // racy read; monotone decreasing -> safe filter
            if (v < cur) atomicMin(&gbest[t], v);
        }
    }
}

__global__ __launch_bounds__(1024) void k_finalize(const float4* __restrict__ emb4,
                                                   const int* __restrict__ min1,
                                                   const int* __restrict__ min2,
                                                   const int* __restrict__ cntPos,
                                                   const int* __restrict__ cntSbj,
                                                   const unsigned long long* __restrict__ best,
                                                   float* out, int B) {
    __shared__ float vals[NUM_PAIRS];
    __shared__ int vld[NUM_PAIRS];
    int wave = threadIdx.x >> 6;
    int lane = threadIdx.x & 63;
    for (int p = wave; p < NUM_PAIRS; p += (blockDim.x >> 6)) {
        int s = p / NUM_CLASSES;
        int ai = min1[p], pi = min2[p];
        int npos = cntPos[p];
        int nneg = cntSbj[s] - npos;
        unsigned long long bb = best[p];
        int ni = (int)(bb & 0xffffffffu);
        bool ok = (npos >= 2) && (nneg >= 1) && (bb != ~0ull);
        if (ai < 0 || ai >= B) ai = 0;
        if (pi < 0 || pi >= B) pi = 0;
        if (ni < 0 || ni >= B) ni = 0;
        float4 a = emb4[(size_t)ai * 64 + lane];
        float4 pp = emb4[(size_t)pi * 64 + lane];
        float4 nn = emb4[(size_t)ni * 64 + lane];
        float dap = 0.f, dan = 0.f, t;
        t = a.x - pp.x + EPS; dap += t * t;
        t = a.y - pp.y + EPS; dap += t * t;
        t = a.z - pp.z + EPS; dap += t * t;
        t = a.w - pp.w + EPS; dap += t * t;
        t = a.x - nn.x + EPS; dan += t * t;
        t = a.y - nn.y + EPS; dan += t * t;
        t = a.z - nn.z + EPS; dan += t * t;
        t = a.w - nn.w + EPS; dan += t * t;
        dap = wredsum(dap);
        dan = wredsum(dan);
        if (lane == 0) {
            float lv = sqrtf(dap) - sqrtf(dan) + MARGIN;
            vals[p] = ok ? fmaxf(lv, 0.f) : 0.f;
            vld[p] = ok ? 1 : 0;
        }
    }
    __syncthreads();
    if (threadIdx.x == 0) {
        float sum = 0.f;
        int cnt = 0;
        for (int p = 0; p < NUM_PAIRS; ++p) { sum += vals[p]; cnt += vld[p]; }
        out[0] = (cnt > 0) ? (sum / (float)cnt) : 0.f;
    }
}

extern "C" void kernel_launch(void* const* d_in, const int* in_sizes, int n_in,
                              void* d_out, int out_size, void* d_ws, size_t ws_size,
                              hipStream_t stream) {
    const float* emb = (const float*)d_in[0];
    const int* labels = (const int*)d_in[1];
    const int* sbj = (const int*)d_in[2];
    float* out = (float*)d_out;
    const int B = in_sizes[1];           // 131072
    const float4* emb4 = (const float4*)emb;

    char* ws = (char*)d_ws;
    int* min1 = (int*)(ws + 0);
    int* min2 = (int*)(ws + 384);
    int* cntPos = (int*)(ws + 768);
    int* cntSbj = (int*)(ws + 1152);
    unsigned long long* best = (unsigned long long*)(ws + 1216);
    float* a2 = (float*)(ws + 1984);
    float4* anchors4 = (float4*)(ws + 2432);

    k_init<<<1, 128, 0, stream>>>(min1, min2, cntPos, cntSbj, best, a2);

    int blk = 256;
    int grd = (B + blk - 1) / blk;
    k_stats<<<grd, blk, 0, stream>>>(labels, sbj, min1, min2, cntPos, cntSbj, B);

    k_gather<<<NUM_PAIRS, 64, 0, stream>>>(emb4, min1, anchors4, a2, B);

    int mblocks = (B + 255) / 256;       // 256 samples per block (8 waves x 32)
    k_mine<<<mblocks, 512, 0, stream>>>(emb4, labels, sbj, anchors4, a2, best, B);

    k_finalize<<<1, 1024, 0, stream>>>(emb4, min1, min2, cntPos, cntSbj, best, out, B);
}

// Round 7
// 71.656 us; speedup vs baseline: 1.1320x; 1.1320x over previous
//
#include <hip/hip_runtime.h>

#define NUM_CLASSES 6
#define NUM_SUBJECTS 16
#define NUM_PAIRS (NUM_CLASSES * NUM_SUBJECTS)   // 96
#define MARGIN 1.0f
#define EPS 1e-6f
#define INF_I 0x7fffffff

typedef _Float16 h2_t __attribute__((ext_vector_type(2)));

// ---------------- ws layout (bytes) ----------------
// [0)      int   min1[96]
// [384)    int   min2[96]
// [768)    int   cntPos[96]
// [1152)   int   cntSbj[16]
// [1216)   u64   best[96]        packed (sortable_f32(d2)<<32)|idx
// [1984)   float a2[96]
// [2432)   f32   anchors[96*256] (float4-aligned)

__device__ __forceinline__ float wredsum(float v) {
#pragma unroll
    for (int m = 32; m >= 1; m >>= 1) v += __shfl_xor(v, m, 64);
    return v;
}

__device__ __forceinline__ unsigned int fkey(float f) {
    unsigned int b = __float_as_uint(f);
    return (b & 0x80000000u) ? ~b : (b | 0x80000000u);
}

// f32 pair -> packed f16x2 (RTZ pack instr), as _Float16 vector via bit_cast
__device__ __forceinline__ h2_t pk16(float x, float y) {
    return __builtin_bit_cast(h2_t, __builtin_amdgcn_cvt_pkrtz(x, y));
}

__global__ void k_init(int* min1, int* min2, int* cntPos, int* cntSbj,
                       unsigned long long* best, float* a2) {
    int t = threadIdx.x;
    if (t < NUM_PAIRS) {
        min1[t] = INF_I;
        min2[t] = INF_I;
        cntPos[t] = 0;
        best[t] = ~0ull;
        a2[t] = 0.f;
    }
    if (t < NUM_SUBJECTS) cntSbj[t] = 0;
}

// Fused: first-two-positive mining + counts, single pass.
__global__ __launch_bounds__(1024) void k_stats(const int* __restrict__ labels,
                                                const int* __restrict__ sbj,
                                                int* min1, int* min2, int* cntPos,
                                                int* cntSbj, int B) {
    __shared__ int l1[NUM_PAIRS], l2[NUM_PAIRS], lcp[NUM_PAIRS], lcs[NUM_SUBJECTS];
    for (int t = threadIdx.x; t < NUM_PAIRS; t += blockDim.x) { l1[t] = INF_I; l2[t] = INF_I; lcp[t] = 0; }
    if (threadIdx.x < NUM_SUBJECTS) lcs[threadIdx.x] = 0;
    __syncthreads();
    for (int i = blockIdx.x * blockDim.x + threadIdx.x; i < B; i += gridDim.x * blockDim.x) {
        int s = sbj[i], c = labels[i];
        int p = s * NUM_CLASSES + c;
        int o = atomicMin(&l1[p], i);
        atomicMin(&l2[p], max(o, i));   // max(INF,i)=INF -> no-op on first insert
        atomicAdd(&lcp[p], 1);
        atomicAdd(&lcs[s], 1);
    }
    __syncthreads();
    for (int t = threadIdx.x; t < NUM_PAIRS; t += blockDim.x) {
        int m1 = l1[t];
        if (m1 != INF_I) {
            int o = atomicMin(&min1[t], m1);
            atomicMin(&min2[t], max(o, m1));
            if (l2[t] != INF_I) atomicMin(&min2[t], l2[t]);
            atomicAdd(&cntPos[t], lcp[t]);
        }
    }
    if (threadIdx.x < NUM_SUBJECTS && lcs[threadIdx.x]) atomicAdd(&cntSbj[threadIdx.x], lcs[threadIdx.x]);
}

__global__ void k_gather(const float4* __restrict__ emb4, const int* __restrict__ min1,
                         float4* anchors4, float* a2, int B) {
    int p = blockIdx.x;          // 96 blocks
    int lane = threadIdx.x;      // 64 threads
    int idx = min1[p];
    if (idx < 0 || idx >= B) idx = 0;
    float4 v = emb4[(size_t)idx * 64 + lane];
    anchors4[(size_t)p * 64 + lane] = v;
    float t = v.x * v.x + v.y * v.y + v.z * v.z + v.w * v.w;
    t = wredsum(t);
    if (lane == 0) a2[p] = t;
}

// Coalesced streaming mine: 16 lanes per sample, 4 samples per wave.
// q = lane&15 indexes CONSECUTIVE float4s, so at each k-step one sample's 16
// lanes read a contiguous 256 B chunk; the wave reads 4 chunks = 16 fully
// consumed cache lines per instruction (coalescing ideal). Reduction over q
// is a 4-step shfl_xor butterfly. Anchors f16 in LDS, u64[s*385 + c*64 + e]
// (subject stride 3080 B -> subjects spread across bank pairs).
__global__ __launch_bounds__(512, 6) void k_mine(const float4* __restrict__ emb4,
                                                 const int* __restrict__ labels,
                                                 const int* __restrict__ sbj,
                                                 const float4* __restrict__ anchors4,
                                                 const float* __restrict__ a2,
                                                 unsigned long long* gbest, int B) {
    __shared__ unsigned long long ancB[NUM_SUBJECTS * 385];   // 49280 B
    __shared__ float a2l[NUM_PAIRS];
    __shared__ unsigned long long lbest[NUM_PAIRS];

    // stage anchors f32 -> f16x4 (pkrtz) packed u64
    for (int u = threadIdx.x; u < NUM_PAIRS * 64; u += blockDim.x) {
        int row = u >> 6;            // s*6+c
        int e = u & 63;              // u64 index within row (4 dims)
        float4 v = anchors4[u];
        unsigned int lou = __builtin_bit_cast(unsigned int, pk16(v.x, v.y));
        unsigned int hiu = __builtin_bit_cast(unsigned int, pk16(v.z, v.w));
        int s = row / NUM_CLASSES, c = row - s * NUM_CLASSES;
        ancB[s * 385 + c * 64 + e] = (unsigned long long)lou | ((unsigned long long)hiu << 32);
    }
    for (int t = threadIdx.x; t < NUM_PAIRS; t += blockDim.x) {
        a2l[t] = a2[t];
        lbest[t] = ~0ull;
    }
    __syncthreads();

    const int lane = threadIdx.x & 63;
    const int q = lane & 15;                        // float4 sub-index
    const int sloc = lane >> 4;                     // 0..3 sample-in-wave
    const int wv = (int)(threadIdx.x >> 6);         // 0..7
    const int waveGlob = (int)blockIdx.x * 8 + wv;
    const int nwv = (int)gridDim.x * 8;

    for (int base = waveGlob * 4; base < B; base += nwv * 4) {
        int row = base + sloc;
        bool valid = row < B;
        int ic = valid ? row : (B - 1);
        int s = sbj[ic];
        int lbl = labels[ic];
        const float4* rp = emb4 + (size_t)ic * 64 + q;
        const unsigned long long* anc = ancB + s * 385 + q;

        float e2 = 0.f, d0 = 0.f, d1 = 0.f, d2v = 0.f, d3 = 0.f, d4 = 0.f, d5 = 0.f;
#pragma unroll
        for (int k = 0; k < 4; ++k) {
            float4 v = rp[k * 16];
            e2 = fmaf(v.x, v.x, fmaf(v.y, v.y, fmaf(v.z, v.z, fmaf(v.w, v.w, e2))));
            h2_t vlo = pk16(v.x, v.y);
            h2_t vhi = pk16(v.z, v.w);
            unsigned long long A;
            h2_t alo, ahi;
#if __has_builtin(__builtin_amdgcn_fdot2)
#define DOT(C, ACC)                                                              \
            A = anc[(C) * 64 + k * 16];                                          \
            alo = __builtin_bit_cast(h2_t, (unsigned int)A);                     \
            ahi = __builtin_bit_cast(h2_t, (unsigned int)(A >> 32));             \
            ACC = __builtin_amdgcn_fdot2(alo, vlo,                               \
                  __builtin_amdgcn_fdot2(ahi, vhi, ACC, false), false);
#else
#define DOT(C, ACC)                                                              \
            A = anc[(C) * 64 + k * 16];                                          \
            alo = __builtin_bit_cast(h2_t, (unsigned int)A);                     \
            ahi = __builtin_bit_cast(h2_t, (unsigned int)(A >> 32));             \
            ACC = fmaf((float)alo.x, v.x, fmaf((float)alo.y, v.y,                \
                  fmaf((float)ahi.x, v.z, fmaf((float)ahi.y, v.w, ACC))));
#endif
            DOT(0, d0) DOT(1, d1) DOT(2, d2v) DOT(3, d3) DOT(4, d4) DOT(5, d5)
#undef DOT
        }
        // reduce over the 16 q-lanes (butterfly: all lanes end with the sum)
#pragma unroll
        for (int m = 1; m <= 8; m <<= 1) {
            e2  += __shfl_xor(e2, m, 64);
            d0  += __shfl_xor(d0, m, 64);
            d1  += __shfl_xor(d1, m, 64);
            d2v += __shfl_xor(d2v, m, 64);
            d3  += __shfl_xor(d3, m, 64);
            d4  += __shfl_xor(d4, m, 64);
            d5  += __shfl_xor(d5, m, 64);
        }

        if (valid && q == 0) {
            int pb = s * NUM_CLASSES;
            float dc[NUM_CLASSES] = {d0, d1, d2v, d3, d4, d5};
#pragma unroll
            for (int c = 0; c < NUM_CLASSES; ++c) {
                if (c != lbl) {
                    float dd = a2l[pb + c] + e2 - 2.f * dc[c];
                    unsigned long long pk =
                        ((unsigned long long)fkey(dd) << 32) | (unsigned int)row;
                    atomicMin(&lbest[pb + c], pk);
                }
            }
        }
    }
    __syncthreads();
    for (int t = threadIdx.x; t < NUM_PAIRS; t += blockDim.x) {
        unsigned long long v = lbest[t];
        if (v != ~0ull) {
            unsigned long long cur = gbest[t];   // racy read; monotone decreasing -> safe filter
            if (v < cur) atomicMin(&gbest[t], v);
        }
    }
}

__global__ __launch_bounds__(1024) void k_finalize(const float4* __restrict__ emb4,
                                                   const int* __restrict__ min1,
                                                   const int* __restrict__ min2,
                                                   const int* __restrict__ cntPos,
                                                   const int* __restrict__ cntSbj,
                                                   const unsigned long long* __restrict__ best,
                                                   float* out, int B) {
    __shared__ float vals[NUM_PAIRS];
    __shared__ int vld[NUM_PAIRS];
    int wave = threadIdx.x >> 6;
    int lane = threadIdx.x & 63;
    for (int p = wave; p < NUM_PAIRS; p += (blockDim.x >> 6)) {
        int s = p / NUM_CLASSES;
        int ai = min1[p], pi = min2[p];
        int npos = cntPos[p];
        int nneg = cntSbj[s] - npos;
        unsigned long long bb = best[p];
        int ni = (int)(bb & 0xffffffffu);
        bool ok = (npos >= 2) && (nneg >= 1) && (bb != ~0ull);
        if (ai < 0 || ai >= B) ai = 0;
        if (pi < 0 || pi >= B) pi = 0;
        if (ni < 0 || ni >= B) ni = 0;
        float4 a = emb4[(size_t)ai * 64 + lane];
        float4 pp = emb4[(size_t)pi * 64 + lane];
        float4 nn = emb4[(size_t)ni * 64 + lane];
        float dap = 0.f, dan = 0.f, t;
        t = a.x - pp.x + EPS; dap += t * t;
        t = a.y - pp.y + EPS; dap += t * t;
        t = a.z - pp.z + EPS; dap += t * t;
        t = a.w - pp.w + EPS; dap += t * t;
        t = a.x - nn.x + EPS; dan += t * t;
        t = a.y - nn.y + EPS; dan += t * t;
        t = a.z - nn.z + EPS; dan += t * t;
        t = a.w - nn.w + EPS; dan += t * t;
        dap = wredsum(dap);
        dan = wredsum(dan);
        if (lane == 0) {
            float lv = sqrtf(dap) - sqrtf(dan) + MARGIN;
            vals[p] = ok ? fmaxf(lv, 0.f) : 0.f;
            vld[p] = ok ? 1 : 0;
        }
    }
    __syncthreads();
    if (threadIdx.x == 0) {
        float sum = 0.f;
        int cnt = 0;
        for (int p = 0; p < NUM_PAIRS; ++p) { sum += vals[p]; cnt += vld[p]; }
        out[0] = (cnt > 0) ? (sum / (float)cnt) : 0.f;
    }
}

extern "C" void kernel_launch(void* const* d_in, const int* in_sizes, int n_in,
                              void* d_out, int out_size, void* d_ws, size_t ws_size,
                              hipStream_t stream) {
    const float* emb = (const float*)d_in[0];
    const int* labels = (const int*)d_in[1];
    const int* sbj = (const int*)d_in[2];
    float* out = (float*)d_out;
    const int B = in_sizes[1];           // 131072
    const float4* emb4 = (const float4*)emb;

    char* ws = (char*)d_ws;
    int* min1 = (int*)(ws + 0);
    int* min2 = (int*)(ws + 384);
    int* cntPos = (int*)(ws + 768);
    int* cntSbj = (int*)(ws + 1152);
    unsigned long long* best = (unsigned long long*)(ws + 1216);
    float* a2 = (float*)(ws + 1984);
    float4* anchors4 = (float4*)(ws + 2432);

    k_init<<<1, 128, 0, stream>>>(min1, min2, cntPos, cntSbj, best, a2);

    k_stats<<<128, 1024, 0, stream>>>(labels, sbj, min1, min2, cntPos, cntSbj, B);

    k_gather<<<NUM_PAIRS, 64, 0, stream>>>(emb4, min1, anchors4, a2, B);

    // 1024 blocks x 8 waves x 4 samples = 32768 samples/round -> 4 rounds
    k_mine<<<1024, 512, 0, stream>>>(emb4, labels, sbj, anchors4, a2, best, B);

    k_finalize<<<1, 1024, 0, stream>>>(emb4, min1, min2, cntPos, cntSbj, best, out, B);
}